// Round 1
// baseline (395.796 us; speedup 1.0000x reference)
//
#include <hip/hip_runtime.h>
#include <math.h>

// Problem constants (B=4, L=8192, SEG=2048, RATE=4, D=768)
#define SEGLEN 2048
#define SRATE 4
#define DIM 768
#define BATCH 4
#define LFULL 8192
#define LSP 2048                 // sparsified length per batch (4 segs * 512)
#define NROWS (BATCH * LSP)      // 8192 total sparsified rows
#define LN_EPS 1e-5f
#define ATT_SCALE 0.03608439182435161f   // 1/sqrt(768)

typedef __attribute__((ext_vector_type(8))) short s16x8;
typedef __attribute__((ext_vector_type(4))) float f32x4;

__device__ __forceinline__ ushort f2bf(float f) {
    unsigned u = __float_as_uint(f);
    u += 0x7fffu + ((u >> 16) & 1u);      // RNE
    return (ushort)(u >> 16);
}
__device__ __forceinline__ float bf2f(ushort h) {
    return __uint_as_float(((unsigned)h) << 16);
}

// async global->LDS, 16B per lane. LDS dest is wave-uniform base + lane*16.
__device__ __forceinline__ void ld_lds16(const ushort* g, ushort* l) {
    __builtin_amdgcn_global_load_lds(
        (const __attribute__((address_space(1))) void*)g,
        (__attribute__((address_space(3))) void*)l, 16, 0, 0);
}

// ---------------------------------------------------------------------------
// Gather sparsified rows (every RATE-th within each segment) + fp32->bf16.
// ---------------------------------------------------------------------------
__global__ void pack3(const float* __restrict__ Q, const float* __restrict__ Ks,
                      const float* __restrict__ V, ushort* __restrict__ X) {
    const float* src = blockIdx.z == 0 ? Q : blockIdx.z == 1 ? Ks : V;
    ushort* dst = X + (long)blockIdx.z * (NROWS * DIM);
    int idx = blockIdx.x * 256 + threadIdx.x;        // one per 4 elements
    int r  = idx / (DIM / 4);
    int dg = idx - r * (DIM / 4);
    int bb = r >> 11;            // /2048
    int s  = r & 2047;
    int seg = s >> 9;            // /512
    int j   = s & 511;
    long srow = (long)bb * LFULL + seg * SEGLEN + j * SRATE;
    float4 f = *(const float4*)(src + srow * DIM + dg * 4);
    ushort4 o;
    o.x = f2bf(f.x); o.y = f2bf(f.y); o.z = f2bf(f.z); o.w = f2bf(f.w);
    *(ushort4*)(dst + (long)r * DIM + dg * 4) = o;
}

// weights fp32 -> bf16, z selects Wq/Wk/Wv; dst contiguous
__global__ void conv3(const float* __restrict__ Wq, const float* __restrict__ Wk,
                      const float* __restrict__ Wv, ushort* __restrict__ W) {
    const float* src = blockIdx.z == 0 ? Wq : blockIdx.z == 1 ? Wk : Wv;
    ushort* dst = W + (long)blockIdx.z * (DIM * DIM);
    int idx = blockIdx.x * 256 + threadIdx.x;
    float4 f = *(const float4*)(src + (long)idx * 4);
    ushort4 o;
    o.x = f2bf(f.x); o.y = f2bf(f.y); o.z = f2bf(f.z); o.w = f2bf(f.w);
    *(ushort4*)(dst + (long)idx * 4) = o;
}

// ---------------------------------------------------------------------------
// BT-GEMM, 256x256 tile, BK=64, 512 thr = 8 waves (2M x 4N), each wave 128x64.
// 8-phase schedule (T2+T3+T4+T5):
//   - per K-tile: 4 phases of {ds_read subtile, 2x global_load_lds, barrier,
//     setprio(1) 16xMFMA setprio(0), barrier}; counted vmcnt(4) only at tile
//     boundary (never 0 in steady state).
//   - LDS st_16x32 XOR-swizzle: subtiled [16rows x 32cols] 1024B chunks,
//     byte ^= ((byte>>9)&1)<<5. gload_lds writes LINEAR dest; the global
//     SOURCE offsets are inverse-swizzled; ds_read applies the swizzle
//     (both-sides rule, m201/m104).
//   - staging: A(v+1) issued phases 0-1 into buf^1 (prev A reads done at end
//     of prev tile); B(v+2) issued phases 2-3 into same buf (B fully consumed
//     in phase 0 behind a barrier).
// MODE 0: z<2 -> bf16 row-major to Cb+z*sC; z==2 -> transposed vT to Cb2 [proj]
// MODE 2: e=__expf(acc*scale); bf16 P row-major + atomicAdd row-sums     [QK]
// MODE 3: split-K: z=(batch,half); fp32 row-major to (half? Cf2 : Cf)   [PV]
// ---------------------------------------------------------------------------
template<int MODE>
__global__ __launch_bounds__(512, 2) void gemm8(
    const ushort* __restrict__ Ag, const ushort* __restrict__ Bg,
    ushort* __restrict__ Cb, ushort* __restrict__ Cb2,
    float* __restrict__ Cf, float* __restrict__ Cf2, float* __restrict__ lsum,
    int M, int N, int K, int lda, int ldb, long sA, long sB, long sC,
    int ldc, float scale)
{
    __shared__ ushort lds[2][2][16384];   // [dbuf][A/B][32KB] = 128 KiB

    const int z = blockIdx.z;
    const int bz = (MODE == 3) ? (z >> 1) : z;
    const int hz = (MODE == 3) ? (z & 1) : 0;
    const ushort* Aop = Ag + (long)bz * sA + (long)hz * K;
    const ushort* Bop = Bg + (long)bz * sB + (long)hz * K;

    const int tid = threadIdx.x;
    const int w = tid >> 6, lane = tid & 63;
    const int wm = w >> 2, wn = w & 3;          // 2 x 4 wave grid
    const int quad = lane >> 4, lr = lane & 15;
    const int rowBase = blockIdx.y * 256;
    const int colBase = blockIdx.x * 256;

    // per-lane ds_read byte offset within a 1024B (16x32) subtile, swizzled
    int ib = ((lane & 15) << 6) | ((lane >> 4) << 4);
    ib ^= ((ib >> 9) & 1) << 5;

    // staging: chunk c = i*512+tid (linear 16B LDS dest). Source offset is
    // computed from the INVERSE-swizzled chunk so reads see st_16x32 layout.
    long offA[4], offB[4];
#pragma unroll
    for (int i = 0; i < 4; i++) {
        int c = i * 512 + tid;
        int cc = c ^ (((c >> 5) & 1) << 1);      // byte-bit5 flip == chunk-bit1
        int s = cc >> 6;                          // subtile index (16 rowgrp x 2 colgrp)
        int row  = ((s >> 1) << 4) + ((cc >> 2) & 15);
        int colE = ((s & 1) << 5) + ((cc & 3) << 3);
        offA[i] = (long)(rowBase + row) * lda + colE;
        offB[i] = (long)(colBase + row) * ldb + colE;
    }

    const int NT = K >> 6;   // K-tiles of 64 (always >= 3 here: 12 or 16)

#define STA(buf, vv, i) ld_lds16(Aop + offA[i] + (long)(vv) * 64, &lds[buf][0][(i) * 4096 + w * 512])
#define STB(buf, vv, i) ld_lds16(Bop + offB[i] + (long)(vv) * 64, &lds[buf][1][(i) * 4096 + w * 512])

    // prologue: B(0) A(0) B(1) A(1); wait only the first two (counted vmcnt)
#pragma unroll
    for (int i = 0; i < 4; i++) STB(0, 0, i);
#pragma unroll
    for (int i = 0; i < 4; i++) STA(0, 0, i);
#pragma unroll
    for (int i = 0; i < 4; i++) STB(1, 1, i);
#pragma unroll
    for (int i = 0; i < 4; i++) STA(1, 1, i);
    asm volatile("s_waitcnt vmcnt(8)" ::: "memory");
    __builtin_amdgcn_s_barrier();

    f32x4 acc[8][4] = {};
    s16x8 bq[4][2];

    for (int v = 0; v < NT; ++v) {
        const int b = v & 1;
        const char* lA = (const char*)&lds[b][0][0];
        const char* lB = (const char*)&lds[b][1][0];
#pragma unroll
        for (int p = 0; p < 4; ++p) {
            s16x8 aq[2][2];
#pragma unroll
            for (int t = 0; t < 2; ++t)
#pragma unroll
                for (int ks = 0; ks < 2; ++ks)
                    aq[t][ks] = *(const s16x8*)(lA + (((wm * 8 + p * 2 + t) * 2 + ks) << 10) + ib);
            if (p == 0) {
#pragma unroll
                for (int n = 0; n < 4; ++n)
#pragma unroll
                    for (int ks = 0; ks < 2; ++ks)
                        bq[n][ks] = *(const s16x8*)(lB + (((wn * 4 + n) * 2 + ks) << 10) + ib);
            }
            // staging: A one tile ahead (A(1) was pre-staged in prologue),
            // B two tiles ahead (its LDS region freed after phase 0's barrier)
            if (p == 0 && v >= 1 && v + 1 < NT) { STA(b ^ 1, v + 1, 0); STA(b ^ 1, v + 1, 1); }
            if (p == 1 && v >= 1 && v + 1 < NT) { STA(b ^ 1, v + 1, 2); STA(b ^ 1, v + 1, 3); }
            if (p == 2 && v + 2 < NT)           { STB(b,     v + 2, 0); STB(b,     v + 2, 1); }
            if (p == 3 && v + 2 < NT)           { STB(b,     v + 2, 2); STB(b,     v + 2, 3); }

            __builtin_amdgcn_s_barrier();
            __builtin_amdgcn_s_setprio(1);
#pragma unroll
            for (int t = 0; t < 2; ++t)
#pragma unroll
                for (int n = 0; n < 4; ++n)
#pragma unroll
                    for (int ks = 0; ks < 2; ++ks)
                        acc[p * 2 + t][n] = __builtin_amdgcn_mfma_f32_16x16x32_bf16(
                            aq[t][ks], bq[n][ks], acc[p * 2 + t][n], 0, 0, 0);
            __builtin_amdgcn_s_setprio(0);
            if (p == 3) {   // tile boundary: counted wait, never 0 in steady state
                if (v + 2 < NT)      asm volatile("s_waitcnt vmcnt(4)" ::: "memory");
                else if (v + 1 < NT) asm volatile("s_waitcnt vmcnt(0)" ::: "memory");
            }
            __builtin_amdgcn_s_barrier();
        }
    }
#undef STA
#undef STB

    // Epilogue. D mapping: col = lane&15, row = quad*4+reg (guide §3).
    if (MODE == 0) {
        if (z < 2) {
            ushort* Cz = Cb + (long)z * sC;
#pragma unroll
            for (int i = 0; i < 8; i++) {
                int r0 = rowBase + wm * 128 + i * 16 + quad * 4;
#pragma unroll
                for (int j = 0; j < 4; j++) {
                    int c = colBase + wn * 64 + j * 16 + lr;
#pragma unroll
                    for (int reg = 0; reg < 4; reg++)
                        Cz[(long)(r0 + reg) * ldc + c] = f2bf(acc[i][j][reg]);
                }
            }
        } else {
            // v-projection: store transposed vT[b][col][row]
#pragma unroll
            for (int i = 0; i < 8; i++) {
                int r0 = rowBase + wm * 128 + i * 16 + quad * 4;
                int bidx = r0 >> 11;
                int jj = r0 & 2047;
                ushort* Cz = Cb2 + (long)bidx * DIM * LSP;
#pragma unroll
                for (int j = 0; j < 4; j++) {
                    int c = colBase + wn * 64 + j * 16 + lr;
                    ushort4 o;
                    o.x = f2bf(acc[i][j][0]); o.y = f2bf(acc[i][j][1]);
                    o.z = f2bf(acc[i][j][2]); o.w = f2bf(acc[i][j][3]);
                    *(ushort4*)(Cz + (long)c * LSP + jj) = o;
                }
            }
        }
    } else if (MODE == 2) {
        ushort* Cz = Cb + (long)z * sC;
        float* lz = lsum + (long)z * M;
#pragma unroll
        for (int i = 0; i < 8; i++) {
            int r0 = rowBase + wm * 128 + i * 16 + quad * 4;
#pragma unroll
            for (int reg = 0; reg < 4; reg++) {
                float s = 0.f;
#pragma unroll
                for (int j = 0; j < 4; j++) {
                    int c = colBase + wn * 64 + j * 16 + lr;
                    float e = __expf(acc[i][j][reg] * scale);  // |logit|<=sqrt(768): no max needed
                    s += e;
                    Cz[(long)(r0 + reg) * ldc + c] = f2bf(e);
                }
                for (int m = 1; m < 16; m <<= 1) s += __shfl_xor(s, m, 64);
                if (lr == 0) atomicAdd(&lz[r0 + reg], s);
            }
        }
    } else { // MODE 3 split-K
        float* Cz = (hz ? Cf2 : Cf) + (long)bz * sC;
#pragma unroll
        for (int i = 0; i < 8; i++) {
            int r0 = rowBase + wm * 128 + i * 16 + quad * 4;
#pragma unroll
            for (int j = 0; j < 4; j++) {
                int c = colBase + wn * 64 + j * 16 + lr;
#pragma unroll
                for (int reg = 0; reg < 4; reg++)
                    Cz[(long)(r0 + reg) * ldc + c] = acc[i][j][reg];
            }
        }
    }
}

// ---------------------------------------------------------------------------
// In-place LayerNorm over DIM=768 bf16 values. One wave per row (12 elem/lane).
// ---------------------------------------------------------------------------
__global__ __launch_bounds__(256) void ln_inplace(
    ushort* __restrict__ X, const float* __restrict__ gamma,
    const float* __restrict__ beta)
{
    int wid = threadIdx.x >> 6, lane = threadIdx.x & 63;
    int row = blockIdx.x * 4 + wid;
    ushort* xp = X + (long)row * DIM;
    float v[12];
    float s = 0.f;
#pragma unroll
    for (int c = 0; c < 12; c++) { v[c] = bf2f(xp[c * 64 + lane]); s += v[c]; }
    for (int m = 1; m < 64; m <<= 1) s += __shfl_xor(s, m, 64);
    float mean = s * (1.0f / 768.0f);
    float q = 0.f;
#pragma unroll
    for (int c = 0; c < 12; c++) { float d = v[c] - mean; q += d * d; }
    for (int m = 1; m < 64; m <<= 1) q += __shfl_xor(q, m, 64);
    float rstd = rsqrtf(q * (1.0f / 768.0f) + LN_EPS);
#pragma unroll
    for (int c = 0; c < 12; c++) {
        int idx = c * 64 + lane;
        float y = (v[c] - mean) * rstd * gamma[idx] + beta[idx];
        xp[idx] = f2bf(y);
    }
}

// ---------------------------------------------------------------------------
// out[row] = softmax_over_d( (O0[row]+O1[row]) / l[row] ). One wave per row.
// ---------------------------------------------------------------------------
__global__ __launch_bounds__(256) void final_softmax(
    const float* __restrict__ O0, const float* __restrict__ O1,
    const float* __restrict__ l, float* __restrict__ out)
{
    int wid = threadIdx.x >> 6, lane = threadIdx.x & 63;
    int row = blockIdx.x * 4 + wid;
    long base = (long)row * DIM;
    float inv = 1.0f / l[row];
    float v[12]; float mx = -1e30f;
#pragma unroll
    for (int c = 0; c < 12; c++) {
        v[c] = (O0[base + c * 64 + lane] + O1[base + c * 64 + lane]) * inv;
        mx = fmaxf(mx, v[c]);
    }
    for (int m = 1; m < 64; m <<= 1) mx = fmaxf(mx, __shfl_xor(mx, m, 64));
    float s = 0.f;
#pragma unroll
    for (int c = 0; c < 12; c++) { v[c] = __expf(v[c] - mx); s += v[c]; }
    for (int m = 1; m < 64; m <<= 1) s += __shfl_xor(s, m, 64);
    float invs = 1.0f / s;
#pragma unroll
    for (int c = 0; c < 12; c++) out[base + c * 64 + lane] = v[c] * invs;
}

// ---------------------------------------------------------------------------
extern "C" void kernel_launch(void* const* d_in, const int* in_sizes, int n_in,
                              void* d_out, int out_size, void* d_ws, size_t ws_size,
                              hipStream_t stream)
{
    const float* Q  = (const float*)d_in[0];
    const float* K_ = (const float*)d_in[1];
    const float* V  = (const float*)d_in[2];
    const float* Wq = (const float*)d_in[3];
    const float* Wk = (const float*)d_in[4];
    const float* Wv = (const float*)d_in[5];
    const float* g  = (const float*)d_in[6];
    const float* b  = (const float*)d_in[7];
    float* out = (float*)d_out;

    char* ws = (char*)d_ws;
    // Workspace layout (bytes). Total ~104.3 MB.
    // P aliases X (lifetime-disjoint); O1 aliases qb+kb (dead after QK).
    ushort* Xq  = (ushort*)(ws + 0);            // 12,582,912 each (Xq,Xk,Xv contig)
    ushort* Wqb = (ushort*)(ws + 37748736);     // 1,179,648 each (contig)
    ushort* qb  = (ushort*)(ws + 41287680);     // 12,582,912 each (qb,kb contig)
    ushort* kb  = (ushort*)(ws + 53870592);
    ushort* vT  = (ushort*)(ws + 66453504);     // 12,582,912
    float*  O0  = (float*)(ws + 79036416);      // 25,165,824
    float*  l   = (float*)(ws + 104202240);     // 32,768
    ushort* P   = (ushort*)(ws + 0);            // 33,554,432 (alias X)
    float*  O1  = (float*)(ws + 41287680);      // 25,165,824 (alias qb+kb)

    (void)in_sizes; (void)n_in; (void)out_size; (void)ws_size;

    hipMemsetAsync(l, 0, NROWS * sizeof(float), stream);

    // 1) gather sparsified rows -> bf16 (z = Q/K/V)
    pack3<<<dim3(6144, 1, 3), 256, 0, stream>>>(Q, K_, V, Xq);
    // 2) weights -> bf16 (z = Wq/Wk/Wv)
    conv3<<<dim3(576, 1, 3), 256, 0, stream>>>(Wq, Wk, Wv, Wqb);

    // 3) projections: z in {q,k,v}; v stores transposed (vT). 256x256 tiles.
    gemm8<0><<<dim3(DIM / 256, NROWS / 256, 3), 512, 0, stream>>>(
        Xq, Wqb, qb, vT, nullptr, nullptr, nullptr,
        NROWS, DIM, DIM, DIM, DIM,
        (long)NROWS * DIM, (long)DIM * DIM, (long)NROWS * DIM, DIM, 0.f);

    // 4) LayerNorm q and k in place (qb,kb contiguous: 16384 rows)
    ln_inplace<<<4096, 256, 0, stream>>>(qb, g, b);

    // 5) P = exp(scale * q k^T), row-sums into l  (256 blocks = 1/CU)
    gemm8<2><<<dim3(LSP / 256, LSP / 256, BATCH), 512, 0, stream>>>(
        qb, kb, P, nullptr, nullptr, nullptr, l,
        LSP, LSP, DIM, DIM, DIM,
        (long)LSP * DIM, (long)LSP * DIM, (long)LSP * LSP, LSP, ATT_SCALE);

    // 6) O = P @ v, split-K x2 (z = batch*2 + half), B operand = vT
    gemm8<3><<<dim3(DIM / 256, LSP / 256, BATCH * 2), 512, 0, stream>>>(
        P, vT, nullptr, nullptr, O0, O1, nullptr,
        LSP, DIM, LSP / 2, LSP, LSP,
        (long)LSP * LSP, (long)DIM * LSP, (long)LSP * DIM, DIM, 0.f);

    // 7) out = softmax_d((O0+O1) / l)
    final_softmax<<<2048, 256, 0, stream>>>(O0, O1, l, out);
}

// Round 2
// 377.923 us; speedup vs baseline: 1.0473x; 1.0473x over previous
//
#include <hip/hip_runtime.h>
#include <math.h>

// Problem constants (B=4, L=8192, SEG=2048, RATE=4, D=768)
#define SEGLEN 2048
#define SRATE 4
#define DIM 768
#define BATCH 4
#define LFULL 8192
#define LSP 2048                 // sparsified length per batch (4 segs * 512)
#define NROWS (BATCH * LSP)      // 8192 total sparsified rows
#define LN_EPS 1e-5f
#define ATT_SCALE 0.03608439182435161f   // 1/sqrt(768)

typedef __attribute__((ext_vector_type(8))) short s16x8;
typedef __attribute__((ext_vector_type(4))) float f32x4;

__device__ __forceinline__ ushort f2bf(float f) {
    unsigned u = __float_as_uint(f);
    u += 0x7fffu + ((u >> 16) & 1u);      // RNE
    return (ushort)(u >> 16);
}
__device__ __forceinline__ float bf2f(ushort h) {
    return __uint_as_float(((unsigned)h) << 16);
}

// async global->LDS, 16B per lane. LDS dest is wave-uniform base + lane*16.
__device__ __forceinline__ void ld_lds16(const ushort* g, ushort* l) {
    __builtin_amdgcn_global_load_lds(
        (const __attribute__((address_space(1))) void*)g,
        (__attribute__((address_space(3))) void*)l, 16, 0, 0);
}

// ---------------------------------------------------------------------------
// Gather sparsified rows (every RATE-th within each segment) + fp32->bf16.
// ---------------------------------------------------------------------------
__global__ void pack3(const float* __restrict__ Q, const float* __restrict__ Ks,
                      const float* __restrict__ V, ushort* __restrict__ X) {
    const float* src = blockIdx.z == 0 ? Q : blockIdx.z == 1 ? Ks : V;
    ushort* dst = X + (long)blockIdx.z * (NROWS * DIM);
    int idx = blockIdx.x * 256 + threadIdx.x;        // one per 4 elements
    int r  = idx / (DIM / 4);
    int dg = idx - r * (DIM / 4);
    int bb = r >> 11;            // /2048
    int s  = r & 2047;
    int seg = s >> 9;            // /512
    int j   = s & 511;
    long srow = (long)bb * LFULL + seg * SEGLEN + j * SRATE;
    float4 f = *(const float4*)(src + srow * DIM + dg * 4);
    ushort4 o;
    o.x = f2bf(f.x); o.y = f2bf(f.y); o.z = f2bf(f.z); o.w = f2bf(f.w);
    *(ushort4*)(dst + (long)r * DIM + dg * 4) = o;
}

// weights fp32 -> bf16, z selects Wq/Wk/Wv; dst contiguous
__global__ void conv3(const float* __restrict__ Wq, const float* __restrict__ Wk,
                      const float* __restrict__ Wv, ushort* __restrict__ W) {
    const float* src = blockIdx.z == 0 ? Wq : blockIdx.z == 1 ? Wk : Wv;
    ushort* dst = W + (long)blockIdx.z * (DIM * DIM);
    int idx = blockIdx.x * 256 + threadIdx.x;
    float4 f = *(const float4*)(src + (long)idx * 4);
    ushort4 o;
    o.x = f2bf(f.x); o.y = f2bf(f.y); o.z = f2bf(f.z); o.w = f2bf(f.w);
    *(ushort4*)(dst + (long)idx * 4) = o;
}

// ---------------------------------------------------------------------------
// BT-GEMM: C[i][j] = sum_k A[i][k]*B[j][k], bf16 operands K-contiguous.
// 128x128 tile, BK=64, 256 thr = 4 waves (2x2), wave tile 64x64 (acc[4][4]).
// LDS 64 KiB -> 2 blocks/CU co-resident: inter-block overlap hides the
// vmcnt/barrier stalls that capped the 256^2 1-block/CU version at 17% MfmaUtil.
//   - subtiled st_16x32 LDS layout: 1024B subtiles [16 rows][32 elems],
//     swizzle byte ^= ((byte>>9)&1)<<5 applied on ds_read addr; gload_lds
//     writes LINEAR dest, global SOURCE offsets inverse-swizzled (rule #21;
//     measured 0 bank conflicts in round 1).
//   - per K-tile: issue next tile's 8 gload_lds BEFORE compute, one
//     vmcnt(0)+barrier per tile (T3-minimum recipe), setprio(1) around MFMA.
//   - m204 bijective XCD chunking (all grids %8==0): consecutive work ids on
//     one XCD, x-fastest -> A-panel reuse + B working set fits 4MiB L2.
// MODE 0: z<2 -> bf16 row-major to Cb+z*sC; z==2 -> transposed vT to Cb2 [proj]
// MODE 2: e=__expf(acc*scale); bf16 P row-major + atomicAdd row-sums     [QK]
// MODE 3: split-K: z=(batch,half); fp32 row-major to (half? Cf2 : Cf)   [PV]
// ---------------------------------------------------------------------------
template<int MODE>
__global__ __launch_bounds__(256, 2) void gemm_bt(
    const ushort* __restrict__ Ag, const ushort* __restrict__ Bg,
    ushort* __restrict__ Cb, ushort* __restrict__ Cb2,
    float* __restrict__ Cf, float* __restrict__ Cf2, float* __restrict__ lsum,
    int M, int N, int K, int lda, int ldb, long sA, long sB, long sC,
    int ldc, float scale)
{
    __shared__ ushort lds[2][2][8192];   // [dbuf][A/B][16KB] = 64 KiB

    // --- XCD-chunked bijective remap (m204; grid sizes all divisible by 8)
    const int gx = gridDim.x, gy = gridDim.y;
    const int G = gx * gy * gridDim.z;
    const int f = blockIdx.x + gx * (blockIdx.y + gy * blockIdx.z);
    const int wg = (f & 7) * (G >> 3) + (f >> 3);
    const int bx = wg % gx;
    const int rest = wg / gx;
    const int by = rest % gy;
    const int z  = rest / gy;

    const int bz = (MODE == 3) ? (z >> 1) : z;
    const int hz = (MODE == 3) ? (z & 1) : 0;
    const ushort* Aop = Ag + (long)bz * sA + (long)hz * K;
    const ushort* Bop = Bg + (long)bz * sB + (long)hz * K;

    const int tid = threadIdx.x;
    const int wid = tid >> 6, lane = tid & 63;
    const int wm = wid >> 1, wn = wid & 1;      // 2x2 wave grid
    const int quad = lane >> 4, lr = lane & 15;
    const int rowBase = by * 128;
    const int colBase = bx * 128;

    // per-lane ds_read byte offset within a 1024B (16x32) subtile, swizzled
    int ib = ((lane & 15) << 6) | ((lane >> 4) << 4);
    ib ^= ((ib >> 9) & 1) << 5;

    // staging: chunk c = i*256+tid -> linear 16B LDS dest; global source is
    // the inverse-swizzled chunk so ds_reads see st_16x32 layout.
    long offA[4], offB[4];
#pragma unroll
    for (int i = 0; i < 4; i++) {
        int c = i * 256 + tid;
        int cc = c ^ (((c >> 5) & 1) << 1);      // byte-bit5 flip == chunk-bit1
        int s = cc >> 6;                          // subtile idx: 8 rowgrp x 2 kshalf
        int row  = ((s >> 1) << 4) + ((cc >> 2) & 15);
        int colE = ((s & 1) << 5) + ((cc & 3) << 3);
        offA[i] = (long)(rowBase + row) * lda + colE;
        offB[i] = (long)(colBase + row) * ldb + colE;
    }

    const int NT = K >> 6;   // K-tiles of 64 (12 or 16 here)

#define STA(buf, vv, i) ld_lds16(Aop + offA[i] + (long)(vv) * 64, &lds[buf][0][(i) * 2048 + wid * 512])
#define STB(buf, vv, i) ld_lds16(Bop + offB[i] + (long)(vv) * 64, &lds[buf][1][(i) * 2048 + wid * 512])

    // prologue: stage tile 0
#pragma unroll
    for (int i = 0; i < 4; i++) { STA(0, 0, i); STB(0, 0, i); }
    asm volatile("s_waitcnt vmcnt(0)" ::: "memory");
    __builtin_amdgcn_s_barrier();

    f32x4 acc[4][4] = {};

    for (int v = 0; v < NT; ++v) {
        const int b = v & 1;
        // issue next tile's loads first; they complete under this tile's MFMA
        if (v + 1 < NT) {
#pragma unroll
            for (int i = 0; i < 4; i++) { STA(b ^ 1, v + 1, i); STB(b ^ 1, v + 1, i); }
        }
        const char* lA = (const char*)&lds[b][0][0];
        const char* lB = (const char*)&lds[b][1][0];
#pragma unroll
        for (int ks = 0; ks < 2; ++ks) {
            s16x8 af[4], bfm[4];
#pragma unroll
            for (int t = 0; t < 4; ++t)
                af[t] = *(const s16x8*)(lA + (((wm * 4 + t) * 2 + ks) << 10) + ib);
#pragma unroll
            for (int t = 0; t < 4; ++t)
                bfm[t] = *(const s16x8*)(lB + (((wn * 4 + t) * 2 + ks) << 10) + ib);
            __builtin_amdgcn_s_setprio(1);
#pragma unroll
            for (int i = 0; i < 4; i++)
#pragma unroll
                for (int j = 0; j < 4; j++)
                    acc[i][j] = __builtin_amdgcn_mfma_f32_16x16x32_bf16(
                        af[i], bfm[j], acc[i][j], 0, 0, 0);
            __builtin_amdgcn_s_setprio(0);
        }
        if (v + 1 < NT) asm volatile("s_waitcnt vmcnt(0)" ::: "memory");
        __builtin_amdgcn_s_barrier();
    }
#undef STA
#undef STB

    // Epilogue. D mapping: col = lane&15, row = quad*4+reg (guide §3).
    if (MODE == 0) {
        if (z < 2) {
            ushort* Cz = Cb + (long)z * sC;
#pragma unroll
            for (int i = 0; i < 4; i++) {
                int r0 = rowBase + wm * 64 + i * 16 + quad * 4;
#pragma unroll
                for (int j = 0; j < 4; j++) {
                    int c = colBase + wn * 64 + j * 16 + lr;
#pragma unroll
                    for (int reg = 0; reg < 4; reg++)
                        Cz[(long)(r0 + reg) * ldc + c] = f2bf(acc[i][j][reg]);
                }
            }
        } else {
            // v-projection: store transposed vT[b][col][row]
#pragma unroll
            for (int i = 0; i < 4; i++) {
                int r0 = rowBase + wm * 64 + i * 16 + quad * 4;
                int bidx = r0 >> 11;
                int jj = r0 & 2047;
                ushort* Cz = Cb2 + (long)bidx * DIM * LSP;
#pragma unroll
                for (int j = 0; j < 4; j++) {
                    int c = colBase + wn * 64 + j * 16 + lr;
                    ushort4 o;
                    o.x = f2bf(acc[i][j][0]); o.y = f2bf(acc[i][j][1]);
                    o.z = f2bf(acc[i][j][2]); o.w = f2bf(acc[i][j][3]);
                    *(ushort4*)(Cz + (long)c * LSP + jj) = o;
                }
            }
        }
    } else if (MODE == 2) {
        ushort* Cz = Cb + (long)z * sC;
        float* lz = lsum + (long)z * M;
#pragma unroll
        for (int i = 0; i < 4; i++) {
            int r0 = rowBase + wm * 64 + i * 16 + quad * 4;
#pragma unroll
            for (int reg = 0; reg < 4; reg++) {
                float s = 0.f;
#pragma unroll
                for (int j = 0; j < 4; j++) {
                    int c = colBase + wn * 64 + j * 16 + lr;
                    float e = __expf(acc[i][j][reg] * scale);  // |logit|<=sqrt(768): no max needed
                    s += e;
                    Cz[(long)(r0 + reg) * ldc + c] = f2bf(e);
                }
                for (int m = 1; m < 16; m <<= 1) s += __shfl_xor(s, m, 64);
                if (lr == 0) atomicAdd(&lz[r0 + reg], s);
            }
        }
    } else { // MODE 3 split-K
        float* Cz = (hz ? Cf2 : Cf) + (long)bz * sC;
#pragma unroll
        for (int i = 0; i < 4; i++) {
            int r0 = rowBase + wm * 64 + i * 16 + quad * 4;
#pragma unroll
            for (int j = 0; j < 4; j++) {
                int c = colBase + wn * 64 + j * 16 + lr;
#pragma unroll
                for (int reg = 0; reg < 4; reg++)
                    Cz[(long)(r0 + reg) * ldc + c] = acc[i][j][reg];
            }
        }
    }
}

// ---------------------------------------------------------------------------
// In-place LayerNorm over DIM=768 bf16 values. One wave per row (12 elem/lane).
// ---------------------------------------------------------------------------
__global__ __launch_bounds__(256) void ln_inplace(
    ushort* __restrict__ X, const float* __restrict__ gamma,
    const float* __restrict__ beta)
{
    int wid = threadIdx.x >> 6, lane = threadIdx.x & 63;
    int row = blockIdx.x * 4 + wid;
    ushort* xp = X + (long)row * DIM;
    float v[12];
    float s = 0.f;
#pragma unroll
    for (int c = 0; c < 12; c++) { v[c] = bf2f(xp[c * 64 + lane]); s += v[c]; }
    for (int m = 1; m < 64; m <<= 1) s += __shfl_xor(s, m, 64);
    float mean = s * (1.0f / 768.0f);
    float q = 0.f;
#pragma unroll
    for (int c = 0; c < 12; c++) { float d = v[c] - mean; q += d * d; }
    for (int m = 1; m < 64; m <<= 1) q += __shfl_xor(q, m, 64);
    float rstd = rsqrtf(q * (1.0f / 768.0f) + LN_EPS);
#pragma unroll
    for (int c = 0; c < 12; c++) {
        int idx = c * 64 + lane;
        float y = (v[c] - mean) * rstd * gamma[idx] + beta[idx];
        xp[idx] = f2bf(y);
    }
}

// ---------------------------------------------------------------------------
// out[row] = softmax_over_d( (O0[row]+O1[row]) / l[row] ). One wave per row.
// ---------------------------------------------------------------------------
__global__ __launch_bounds__(256) void final_softmax(
    const float* __restrict__ O0, const float* __restrict__ O1,
    const float* __restrict__ l, float* __restrict__ out)
{
    int wid = threadIdx.x >> 6, lane = threadIdx.x & 63;
    int row = blockIdx.x * 4 + wid;
    long base = (long)row * DIM;
    float inv = 1.0f / l[row];
    float v[12]; float mx = -1e30f;
#pragma unroll
    for (int c = 0; c < 12; c++) {
        v[c] = (O0[base + c * 64 + lane] + O1[base + c * 64 + lane]) * inv;
        mx = fmaxf(mx, v[c]);
    }
    for (int m = 1; m < 64; m <<= 1) mx = fmaxf(mx, __shfl_xor(mx, m, 64));
    float s = 0.f;
#pragma unroll
    for (int c = 0; c < 12; c++) { v[c] = __expf(v[c] - mx); s += v[c]; }
    for (int m = 1; m < 64; m <<= 1) s += __shfl_xor(s, m, 64);
    float invs = 1.0f / s;
#pragma unroll
    for (int c = 0; c < 12; c++) out[base + c * 64 + lane] = v[c] * invs;
}

// ---------------------------------------------------------------------------
extern "C" void kernel_launch(void* const* d_in, const int* in_sizes, int n_in,
                              void* d_out, int out_size, void* d_ws, size_t ws_size,
                              hipStream_t stream)
{
    const float* Q  = (const float*)d_in[0];
    const float* K_ = (const float*)d_in[1];
    const float* V  = (const float*)d_in[2];
    const float* Wq = (const float*)d_in[3];
    const float* Wk = (const float*)d_in[4];
    const float* Wv = (const float*)d_in[5];
    const float* g  = (const float*)d_in[6];
    const float* b  = (const float*)d_in[7];
    float* out = (float*)d_out;

    char* ws = (char*)d_ws;
    // Workspace layout (bytes). Total ~104.3 MB.
    // P aliases X (lifetime-disjoint); O1 aliases qb+kb (dead after QK).
    ushort* Xq  = (ushort*)(ws + 0);            // 12,582,912 each (Xq,Xk,Xv contig)
    ushort* Wqb = (ushort*)(ws + 37748736);     // 1,179,648 each (contig)
    ushort* qb  = (ushort*)(ws + 41287680);     // 12,582,912 each (qb,kb contig)
    ushort* kb  = (ushort*)(ws + 53870592);
    ushort* vT  = (ushort*)(ws + 66453504);     // 12,582,912
    float*  O0  = (float*)(ws + 79036416);      // 25,165,824
    float*  l   = (float*)(ws + 104202240);     // 32,768
    ushort* P   = (ushort*)(ws + 0);            // 33,554,432 (alias X)
    float*  O1  = (float*)(ws + 41287680);      // 25,165,824 (alias qb+kb)

    (void)in_sizes; (void)n_in; (void)out_size; (void)ws_size;

    hipMemsetAsync(l, 0, NROWS * sizeof(float), stream);

    // 1) gather sparsified rows -> bf16 (z = Q/K/V)
    pack3<<<dim3(6144, 1, 3), 256, 0, stream>>>(Q, K_, V, Xq);
    // 2) weights -> bf16 (z = Wq/Wk/Wv)
    conv3<<<dim3(576, 1, 3), 256, 0, stream>>>(Wq, Wk, Wv, Wqb);

    // 3) projections: z in {q,k,v}; v stores transposed (vT). 1152 blocks.
    gemm_bt<0><<<dim3(DIM / 128, NROWS / 128, 3), 256, 0, stream>>>(
        Xq, Wqb, qb, vT, nullptr, nullptr, nullptr,
        NROWS, DIM, DIM, DIM, DIM,
        (long)NROWS * DIM, (long)DIM * DIM, (long)NROWS * DIM, DIM, 0.f);

    // 4) LayerNorm q and k in place (qb,kb contiguous: 16384 rows)
    ln_inplace<<<4096, 256, 0, stream>>>(qb, g, b);

    // 5) P = exp(scale * q k^T), row-sums into l  (1024 blocks = 4/CU)
    gemm_bt<2><<<dim3(LSP / 128, LSP / 128, BATCH), 256, 0, stream>>>(
        qb, kb, P, nullptr, nullptr, nullptr, l,
        LSP, LSP, DIM, DIM, DIM,
        (long)LSP * DIM, (long)LSP * DIM, (long)LSP * LSP, LSP, ATT_SCALE);

    // 6) O = P @ v, split-K x2 (z = batch*2 + half), B operand = vT (768 blocks)
    gemm_bt<3><<<dim3(DIM / 128, LSP / 128, BATCH * 2), 256, 0, stream>>>(
        P, vT, nullptr, nullptr, O0, O1, nullptr,
        LSP, DIM, LSP / 2, LSP, LSP,
        (long)LSP * LSP, (long)DIM * LSP, (long)LSP * DIM, DIM, 0.f);

    // 7) out = softmax_d((O0+O1) / l)
    final_softmax<<<2048, 256, 0, stream>>>(O0, O1, l, out);
}